// Round 1
// 283.212 us; speedup vs baseline: 1.0568x; 1.0568x over previous
//
#include <hip/hip_runtime.h>
#include <hip/hip_bf16.h>

typedef unsigned short u16;
typedef unsigned int u32;
typedef __attribute__((ext_vector_type(8))) short short8;  // bf16x8 MFMA A/B frag
typedef __attribute__((ext_vector_type(4))) float f32x4;   // MFMA acc / float4
typedef __attribute__((ext_vector_type(4))) int i32x4;     // 16B vector ld/st

__device__ __forceinline__ float b2f(u16 u) {
    union { u32 i; float f; } x; x.i = ((u32)u) << 16; return x.f;
}
__device__ __forceinline__ u16 f2b(float f) {
    union { float f; u32 u; } x; x.f = f;
    u32 r = x.u + 0x7fffu + ((x.u >> 16) & 1u);
    return (u16)(r >> 16);
}
// packed f32x2 -> bf16x2 (v_cvt_pk_bf16_f32), lo = a
__device__ __forceinline__ u32 pkbf(float a, float b) {
    union { __hip_bfloat162 h; u32 u; } x;
    x.h = __float22bfloat162_rn(make_float2(a, b));
    return x.u;
}
// async 16B global->LDS (wave-uniform LDS base + lane*16; m97 pattern)
__device__ __forceinline__ void async_cp16(const u16* g, u16* l) {
    __builtin_amdgcn_global_load_lds(
        (const __attribute__((address_space(1))) void*)g,
        (__attribute__((address_space(3))) void*)l, 16, 0, 0);
}

// ---------------------------------------------------------------------------
// Dtype probe: flag = 1 (fp32 wire) / 0 (bf16 wire).
// ---------------------------------------------------------------------------
__global__ void probe_dtype(const u16* __restrict__ x, int* __restrict__ flag) {
    int bigf = 0;
    for (int i = threadIdx.x; i < 512; i += 64) {
        float v = fabsf(b2f(x[i]));
        if (!(v <= 1e6f)) bigf = 1;
    }
    int any = __any(bigf);
    if (threadIdx.x == 0) *flag = any ? 1 : 0;
}

// ---------------------------------------------------------------------------
// Canonicalize to bf16 (no transpose).
// ---------------------------------------------------------------------------
__global__ __launch_bounds__(256) void canon(
    const void* __restrict__ src, u16* __restrict__ dst, int n,
    const int* __restrict__ flag)
{
    int i = (blockIdx.x * 256 + threadIdx.x) * 8;
    if (i >= n) return;
    if (*flag) {
        const float* s = (const float*)src + i;
        f32x4 a = *(const f32x4*)s;
        f32x4 b = *(const f32x4*)(s + 4);
        union { i32x4 v; u32 w[4]; } o;
        o.w[0] = pkbf(a[0], a[1]); o.w[1] = pkbf(a[2], a[3]);
        o.w[2] = pkbf(b[0], b[1]); o.w[3] = pkbf(b[2], b[3]);
        *(i32x4*)(dst + i) = o.v;
    } else {
        *(i32x4*)(dst + i) = *(const i32x4*)((const u16*)src + i);
    }
}

// ---------------------------------------------------------------------------
// Fused canonicalize + transpose: src [M][N] -> dst [N][M] bf16.
// ---------------------------------------------------------------------------
__global__ __launch_bounds__(256) void canon_t(
    const void* __restrict__ src, u16* __restrict__ dst, int Mdim, int Ndim,
    const int* __restrict__ flag)
{
    __shared__ __align__(16) u16 t[64 * 72];
    const int m0 = blockIdx.x * 64, n0 = blockIdx.y * 64;
    const int tid = threadIdx.x;
    const bool f = (*flag != 0);
#pragma unroll
    for (int p = 0; p < 2; ++p) {
        int s = tid + p * 256;
        int r = s >> 3, c0 = (s & 7) << 3;
        union { i32x4 v; u32 w[4]; } o;
        if (f) {
            const float* sp = (const float*)src + (size_t)(m0 + r) * Ndim + n0 + c0;
            f32x4 a = *(const f32x4*)sp, b = *(const f32x4*)(sp + 4);
            o.w[0] = pkbf(a[0], a[1]); o.w[1] = pkbf(a[2], a[3]);
            o.w[2] = pkbf(b[0], b[1]); o.w[3] = pkbf(b[2], b[3]);
        } else {
            o.v = *(const i32x4*)((const u16*)src + (size_t)(m0 + r) * Ndim + n0 + c0);
        }
        *(i32x4*)(t + r * 72 + c0) = o.v;
    }
    __syncthreads();
#pragma unroll
    for (int p = 0; p < 2; ++p) {
        int s = tid + p * 256;
        int oc = s >> 3, mc = (s & 7) << 3;
        union { i32x4 v; u16 h[8]; } o;
#pragma unroll
        for (int j = 0; j < 8; ++j) o.h[j] = t[(mc + j) * 72 + oc];
        *(i32x4*)(dst + (size_t)(n0 + oc) * Mdim + m0 + mc) = o.v;
    }
}

// ---------------------------------------------------------------------------
// V pre-transpose: qkv[b][s][h*192+128+d] -> vT[h*64+d][b*2048+s].
// ---------------------------------------------------------------------------
__global__ __launch_bounds__(256) void vtrans(
    const u16* __restrict__ qkv, u16* __restrict__ vT)
{
    __shared__ __align__(16) u16 t[64 * 72];
    const int bh = blockIdx.x, b = bh >> 4, h = bh & 15;
    const int s0 = blockIdx.y * 64;
    const int tid = threadIdx.x;
#pragma unroll
    for (int p = 0; p < 2; ++p) {
        int s = tid + p * 256;
        int r = s >> 3, c0 = (s & 7) << 3;
        *(i32x4*)(t + r * 72 + c0) =
            *(const i32x4*)(qkv + (size_t)(b * 2048 + s0 + r) * 3072 + h * 192 + 128 + c0);
    }
    __syncthreads();
#pragma unroll
    for (int p = 0; p < 2; ++p) {
        int s = tid + p * 256;
        int oc = s >> 3, mc = (s & 7) << 3;
        union { i32x4 v; u16 h[8]; } o;
#pragma unroll
        for (int j = 0; j < 8; ++j) o.h[j] = t[(mc + j) * 72 + oc];
        *(i32x4*)(vT + (size_t)(h * 64 + oc) * 8192 + b * 2048 + s0 + mc) = o.v;
    }
}

// ---------------------------------------------------------------------------
// GEMM v2: C[M,N] = A[M,K] * Bt[N,K]^T, bf16, fp32 acc. 128x128 tile, BK=64.
// XOR-swizzled async staging (unchanged).
// ---------------------------------------------------------------------------
__global__ __launch_bounds__(256) void gemm_bf16(
    const u16* __restrict__ A, const u16* __restrict__ Bt, u16* __restrict__ C,
    int M, int N, int K)
{
    __shared__ __align__(16) u16 lA[128 * 64];   // 16 KB
    __shared__ __align__(16) u16 lB[128 * 64];   // 16 KB
    const int tid  = threadIdx.x;
    const int lane = tid & 63;
    const int wave = tid >> 6;
    const int la = lane & 15;
    const int qd = lane >> 4;
    const int m0 = blockIdx.x * 128, n0 = blockIdx.y * 128;
    const int wm = (wave & 1) * 64, wn = (wave >> 1) * 64;

    const int srow = lane >> 3;
    const int scol = ((lane & 7) ^ (lane >> 3)) << 3;   // u16 units
    const u16* gA = A  + (size_t)(m0 + wave * 32 + srow) * K + scol;
    const u16* gB = Bt + (size_t)(n0 + wave * 32 + srow) * K + scol;
    u16* lsA = lA + wave * 32 * 64;
    u16* lsB = lB + wave * 32 * 64;

    f32x4 acc[4][4];
    const f32x4 fz = {0.f, 0.f, 0.f, 0.f};
#pragma unroll
    for (int i = 0; i < 4; ++i)
#pragma unroll
        for (int j = 0; j < 4; ++j) acc[i][j] = fz;

    for (int k0 = 0; k0 < K; k0 += 64) {
        __syncthreads();
#pragma unroll
        for (int c = 0; c < 4; ++c) {
            async_cp16(gA + k0 + (size_t)(c * 8) * K, lsA + c * 8 * 64);
            async_cp16(gB + k0 + (size_t)(c * 8) * K, lsB + c * 8 * 64);
        }
        __syncthreads();

#pragma unroll
        for (int s = 0; s < 2; ++s) {
            short8 af[4], bf[4];
#pragma unroll
            for (int i = 0; i < 4; ++i) {
                int row = wm + i * 16 + la;
                af[i] = *(const short8*)(lA + row * 64 + (((s * 4 + qd) ^ (la & 7)) << 3));
            }
#pragma unroll
            for (int j = 0; j < 4; ++j) {
                int row = wn + j * 16 + la;
                bf[j] = *(const short8*)(lB + row * 64 + (((s * 4 + qd) ^ (la & 7)) << 3));
            }
#pragma unroll
            for (int i = 0; i < 4; ++i)
#pragma unroll
                for (int j = 0; j < 4; ++j)
                    acc[i][j] = __builtin_amdgcn_mfma_f32_16x16x32_bf16(
                        af[i], bf[j], acc[i][j], 0, 0, 0);
        }
    }

#pragma unroll
    for (int i = 0; i < 4; ++i)
#pragma unroll
        for (int j = 0; j < 4; ++j)
#pragma unroll
            for (int r = 0; r < 4; ++r) {
                int row = m0 + wm + i * 16 + qd * 4 + r;
                int col = n0 + wn + j * 16 + la;
                C[(size_t)row * N + col] = f2b(acc[i][j][r]);
            }
}

// ---------------------------------------------------------------------------
// MFMA flash attention v6:
//  - T2: XOR-swizzled LDS (stride 64, 16B-chunk ^ (row&7)); swizzle folded
//    into the global source address so global_load_lds stays linear.
//  - T3-min: 2-phase double-buffered K/V staging via global_load_lds,
//    ONE barrier per k-tile (prefetch next tile before compute).
//  - T13: defer-max (skip O-rescale + m update when tile max <= m_run+4).
//  - T5: setprio(1) around MFMA clusters.
// Paired 64-row q-tiles + XCD-aware (pair,bh) remap kept from v5.
// ---------------------------------------------------------------------------
#define S_LEN 2048
#define D3 3072
#define NEG_BIG (-30000.0f)

__global__ __launch_bounds__(256, 4) void attn_fwd(
    const u16* __restrict__ qkv, const u16* __restrict__ vT,
    u16* __restrict__ outp)
{
    __shared__ __align__(16) u16 Ks[2 * 64 * 64];   // [buf][kcol][d]  16 KB
    __shared__ __align__(16) u16 Vts[2 * 64 * 64];  // [buf][d][kcol]  16 KB
    __shared__ __align__(16) u16 Ps[64 * 64];       // [q][kcol]        8 KB
    const int tid  = threadIdx.x;
    const int lane = tid & 63;
    const int wave = tid >> 6;
    const int la = lane & 15;
    const int qd = lane >> 4;
    // XCD swizzle: lin -> (xcd, idx); bh grouped per XCD
    const int lin = blockIdx.y * 16 + blockIdx.x;
    const int xcd = lin & 7, idx = lin >> 3;
    const int bh = xcd * 8 + (idx >> 4);
    const int px = idx & 15;                 // pair index
    const int b = bh >> 4, h = bh & 15;
    const size_t rowb = (size_t)b * S_LEN * D3;
    const int hq = h * 192;
    const u16* vTp = vT + (size_t)(h * 64) * 8192 + (size_t)b * 2048;
    const f32x4 fz = {0.f, 0.f, 0.f, 0.f};

    // staging geometry: thread covers LDS row (c*32 + tid>>3), phys chunk
    // tid&7; source pre-swizzled so logical chunk = (tid&7)^(row&7).
    const int srow = tid >> 3;
    const int scol = ((tid & 7) ^ (srow & 7)) << 3;                 // u16
    const u16* gK = qkv + rowb + (size_t)srow * D3 + hq + 64 + scol;
    const u16* gV = vTp + (size_t)srow * 8192 + scol;

    const int swz = (la & 7);   // read-side chunk XOR key (row&7 == la&7)

    int cur = 0;
#pragma unroll
    for (int seg = 0; seg < 2; ++seg) {
        const int qt = seg == 0 ? px : 31 - px;
        const int q0 = qt * 64;
        const int qg = q0 + wave * 16 + la;   // this lane's q-row

        // Q fragments in registers, scaled by 0.125 (exact pow2 in bf16)
        short8 bq[2];
#pragma unroll
        for (int s = 0; s < 2; ++s) {
            union { short8 v; u16 h[8]; } u;
            u.v = *(const short8*)(qkv + rowb + (size_t)qg * D3 + hq + s * 32 + qd * 8);
#pragma unroll
            for (int j = 0; j < 8; ++j) u.h[j] = f2b(b2f(u.h[j]) * 0.125f);
            bq[s] = u.v;
        }

        f32x4 Oacc[4];
#pragma unroll
        for (int jd = 0; jd < 4; ++jd) Oacc[jd] = fz;
        float m_run = NEG_BIG, l_run = 0.f;

        __syncthreads();   // all waves done reading LDS (prev seg)
        // prologue: stage tile 0 into buf[cur]
#pragma unroll
        for (int c = 0; c < 2; ++c) {
            async_cp16(gK + (size_t)(c * 32) * D3, Ks + cur * 4096 + c * 2048 + wave * 512);
            async_cp16(gV + (size_t)(c * 32) * 8192, Vts + cur * 4096 + c * 2048 + wave * 512);
        }

        for (int kt = 0; kt <= qt; ++kt) {
            const int k0 = kt * 64;
            __syncthreads();   // drains vmcnt: buf[cur] staged; prev reads done
            if (kt < qt) {     // prefetch next tile into buf[cur^1]
                const int kn = k0 + 64;
#pragma unroll
                for (int c = 0; c < 2; ++c) {
                    async_cp16(gK + (size_t)(kn + c * 32) * D3,
                               Ks + (cur ^ 1) * 4096 + c * 2048 + wave * 512);
                    async_cp16(gV + (size_t)(c * 32) * 8192 + kn,
                               Vts + (cur ^ 1) * 4096 + c * 2048 + wave * 512);
                }
            }
            const u16* KsC  = Ks  + cur * 4096;
            const u16* VtsC = Vts + cur * 4096;

            // ---- S^T = K . Q^T ----
            f32x4 sacc[4];
#pragma unroll
            for (int jm = 0; jm < 4; ++jm) sacc[jm] = fz;
            __builtin_amdgcn_s_setprio(1);
#pragma unroll
            for (int s = 0; s < 2; ++s) {
#pragma unroll
                for (int jm = 0; jm < 4; ++jm) {
                    short8 ak = *(const short8*)(KsC + (jm * 16 + la) * 64 +
                                                 (((s * 4 + qd) ^ swz) << 3));
                    sacc[jm] = __builtin_amdgcn_mfma_f32_16x16x32_bf16(ak, bq[s], sacc[jm], 0, 0, 0);
                }
            }
            __builtin_amdgcn_s_setprio(0);
            if (kt == qt) {   // diagonal tile: causal mask
#pragma unroll
                for (int jm = 0; jm < 4; ++jm)
#pragma unroll
                    for (int r = 0; r < 4; ++r)
                        if (k0 + jm * 16 + qd * 4 + r > qg) sacc[jm][r] = NEG_BIG;
            }

            // ---- softmax: in-reg reduce + 2 shuffles over qd ----
            float mx = fmaxf(fmaxf(fmaxf(sacc[0][0], sacc[0][1]), fmaxf(sacc[0][2], sacc[0][3])),
                             fmaxf(fmaxf(sacc[1][0], sacc[1][1]), fmaxf(sacc[1][2], sacc[1][3])));
            mx = fmaxf(mx, fmaxf(fmaxf(fmaxf(sacc[2][0], sacc[2][1]), fmaxf(sacc[2][2], sacc[2][3])),
                                 fmaxf(fmaxf(sacc[3][0], sacc[3][1]), fmaxf(sacc[3][2], sacc[3][3]))));
            mx = fmaxf(mx, __shfl_xor(mx, 16));
            mx = fmaxf(mx, __shfl_xor(mx, 32));

            // T13 defer-max: only rescale when tile max meaningfully exceeds m_run
            const int skip = __all(mx <= m_run + 4.0f);
            if (!skip) {
                float mnew = fmaxf(m_run, mx);
                float al   = __expf(m_run - mnew);
                float ar[4];
#pragma unroll
                for (int r = 0; r < 4; ++r) ar[r] = __shfl(al, qd * 4 + r);
#pragma unroll
                for (int jd = 0; jd < 4; ++jd)
#pragma unroll
                    for (int r = 0; r < 4; ++r) Oacc[jd][r] *= ar[r];
                l_run *= al;
                m_run = mnew;
            }
            float ssum = 0.f;
#pragma unroll
            for (int jm = 0; jm < 4; ++jm)
#pragma unroll
                for (int r = 0; r < 4; ++r) {
                    float pv = __expf(sacc[jm][r] - m_run);
                    sacc[jm][r] = pv;
                    ssum += pv;
                }
            ssum += __shfl_xor(ssum, 16);
            ssum += __shfl_xor(ssum, 32);
            l_run += ssum;

            // ---- P -> LDS (packed cvt + b64 writes, wave-private rows) ----
            // logical u16 col jm*16+qd*4 -> chunk jm*2+(qd>>1), ^ row&7 swizzle
#pragma unroll
            for (int jm = 0; jm < 4; ++jm) {
                uint2 w;
                w.x = pkbf(sacc[jm][0], sacc[jm][1]);
                w.y = pkbf(sacc[jm][2], sacc[jm][3]);
                *(uint2*)(Ps + (wave * 16 + la) * 64 +
                          ((((jm * 2 + (qd >> 1)) ^ swz)) << 3) + ((qd & 1) << 2)) = w;
            }

            // ---- PV ----
            __builtin_amdgcn_s_setprio(1);
#pragma unroll
            for (int s = 0; s < 2; ++s) {
                short8 ap = *(const short8*)(Ps + (wave * 16 + la) * 64 +
                                             (((s * 4 + qd) ^ swz) << 3));
#pragma unroll
                for (int jd = 0; jd < 4; ++jd) {
                    short8 bv = *(const short8*)(VtsC + (jd * 16 + la) * 64 +
                                                 (((s * 4 + qd) ^ swz) << 3));
                    Oacc[jd] = __builtin_amdgcn_mfma_f32_16x16x32_bf16(ap, bv, Oacc[jd], 0, 0, 0);
                }
            }
            __builtin_amdgcn_s_setprio(0);
            cur ^= 1;
        }

        // epilogue
#pragma unroll
        for (int r = 0; r < 4; ++r) {
            float lr = __shfl(l_run, qd * 4 + r);
            float inv = 1.f / lr;
            size_t orow = (size_t)(b * S_LEN + q0 + wave * 16 + qd * 4 + r) * 1024 + h * 64;
#pragma unroll
            for (int jd = 0; jd < 4; ++jd)
                outp[orow + jd * 16 + la] = f2b(Oacc[jd][r] * inv);
        }
    }
}

// ---------------------------------------------------------------------------
// y = proj + x0 ; LayerNorm over last dim (1024). Output dtype per wire flag.
// ---------------------------------------------------------------------------
__global__ __launch_bounds__(256) void ln_residual(
    const u16* __restrict__ proj, const u16* __restrict__ x0,
    void* __restrict__ out, const int* __restrict__ flag)
{
    __shared__ float red[8];
    __shared__ float stats[2];
    const size_t base = (size_t)blockIdx.x * 1024 + threadIdx.x * 4;
    union { uint2 u; u16 s[4]; } pa, xa;
    pa.u = *(const uint2*)(proj + base);
    xa.u = *(const uint2*)(x0 + base);
    float y[4];
    float s1 = 0.f, s2 = 0.f;
#pragma unroll
    for (int j = 0; j < 4; ++j) {
        y[j] = b2f(pa.s[j]) + b2f(xa.s[j]);
        s1 += y[j];
        s2 += y[j] * y[j];
    }
#pragma unroll
    for (int off = 32; off > 0; off >>= 1) {
        s1 += __shfl_down(s1, off);
        s2 += __shfl_down(s2, off);
    }
    const int wave = threadIdx.x >> 6, lane = threadIdx.x & 63;
    if (lane == 0) { red[wave * 2] = s1; red[wave * 2 + 1] = s2; }
    __syncthreads();
    if (threadIdx.x == 0) {
        float S1 = red[0] + red[2] + red[4] + red[6];
        float S2 = red[1] + red[3] + red[5] + red[7];
        float mean = S1 * (1.f / 1024.f);
        float var  = fmaxf(S2 * (1.f / 1024.f) - mean * mean, 0.f);
        stats[0] = mean;
        stats[1] = rsqrtf(var + 1e-5f);
    }
    __syncthreads();
    float mean = stats[0], inv = stats[1];
    if (*flag) {
        f32x4 o;
#pragma unroll
        for (int j = 0; j < 4; ++j) o[j] = (y[j] - mean) * inv;
        *(f32x4*)((float*)out + base) = o;
    } else {
        union { uint2 u; u16 s[4]; } o;
#pragma unroll
        for (int j = 0; j < 4; ++j) o.s[j] = f2b((y[j] - mean) * inv);
        *(uint2*)((u16*)out + base) = o.u;
    }
}

// ---------------------------------------------------------------------------
extern "C" void kernel_launch(void* const* d_in, const int* in_sizes, int n_in,
                              void* d_out, int out_size, void* d_ws, size_t ws_size,
                              hipStream_t stream) {
    // d_in[3] = src_mask, all-False per spec -> ignored
    char* ws = (char*)d_ws;
    int* flag = (int*)ws;
    u16* cx0  = (u16*)(ws + 256);                 // 8192x1024  bf16 (16 MB)
    u16* wtin = cx0  + (size_t)8192 * 1024;       // W_in^T [3072][1024] (6 MB)
    u16* wto  = wtin + (size_t)3072 * 1024;       // W_o^T  [1024][1024] (2 MB)
    u16* qkv  = wto  + (size_t)1024 * 1024;       // 8192x3072 (48 MB)
    u16* vT   = qkv  + (size_t)8192 * 3072;       // [16*64][8192] (16 MB)
    u16* attn = vT   + (size_t)1024 * 8192;       // 8192x1024 (16 MB)
    u16* proj = qkv;                              // reuse qkv region (K3 after K2)

    dim3 blk(256);
    probe_dtype<<<1, 64, 0, stream>>>((const u16*)d_in[0], flag);
    canon<<<4096, blk, 0, stream>>>(d_in[0], cx0, 8192 * 1024, flag);
    canon_t<<<dim3(16, 48), blk, 0, stream>>>(d_in[1], wtin, 1024, 3072, flag);
    canon_t<<<dim3(16, 16), blk, 0, stream>>>(d_in[2], wto,  1024, 1024, flag);
    // K1: QKV projection
    gemm_bf16<<<dim3(64, 24), blk, 0, stream>>>(cx0, wtin, qkv, 8192, 3072, 1024);
    // V pre-transpose
    vtrans<<<dim3(64, 32), blk, 0, stream>>>(qkv, vT);
    // K2: causal flash attention (2-phase dbuf, XOR-swizzled, defer-max)
    attn_fwd<<<dim3(16, 64), blk, 0, stream>>>(qkv, vT, attn);
    // K3: output projection
    gemm_bf16<<<dim3(64, 8), blk, 0, stream>>>(attn, wto, proj, 8192, 1024, 1024);
    // K4: residual + LayerNorm
    ln_residual<<<dim3(8192), blk, 0, stream>>>(proj, cx0, d_out, flag);
}